// Round 1
// baseline (22694.157 us; speedup 1.0000x reference)
//
#include <hip/hip_runtime.h>
#include <hip/hip_bf16.h>

typedef unsigned short u16;
typedef short short8 __attribute__((ext_vector_type(8)));
typedef u16 u16x8 __attribute__((ext_vector_type(8)));
typedef float f32x4 __attribute__((ext_vector_type(4)));

#define H 1024
#define NB 16
#define SEQ 256
#define NL 4
#define VOCAB 32000
#define G4 4096

__device__ __forceinline__ u16 f2bf(float f) {
  __hip_bfloat16 h = __float2bfloat16(f);
  return *reinterpret_cast<u16*>(&h);
}
__device__ __forceinline__ float sigm(float x) { return 1.0f / (1.0f + __expf(-x)); }
__device__ __forceinline__ float tanhfast(float x) { return 2.0f / (1.0f + __expf(-2.0f * x)) - 1.0f; }

__device__ __forceinline__ f32x4 mfma16(short8 a, short8 b, f32x4 c) {
  return __builtin_amdgcn_mfma_f32_16x16x32_bf16(a, b, c, 0, 0, 0);
}

// ---------------- small prep kernels ----------------

__global__ void cvt_bf16(const float* __restrict__ in, u16* __restrict__ out, int n8) {
  const int i = blockIdx.x * blockDim.x + threadIdx.x;
  if (i >= n8) return;
  const float4 a = ((const float4*)in)[2 * i];
  const float4 b = ((const float4*)in)[2 * i + 1];
  u16x8 o;
  o[0] = f2bf(a.x); o[1] = f2bf(a.y); o[2] = f2bf(a.z); o[3] = f2bf(a.w);
  o[4] = f2bf(b.x); o[5] = f2bf(b.y); o[6] = f2bf(b.z); o[7] = f2bf(b.w);
  *(u16x8*)(out + (size_t)i * 8) = o;
}

__global__ void bias_sum(const float* __restrict__ a, const float* __restrict__ b,
                         float* __restrict__ o, int n) {
  const int i = blockIdx.x * blockDim.x + threadIdx.x;
  if (i < n) o[i] = a[i] + b[i];
}

__global__ void zero_u32(unsigned* __restrict__ p, int n) {
  const int i = blockIdx.x * blockDim.x + threadIdx.x;
  if (i < n) p[i] = 0u;
}

__global__ void gather_emb(const int* __restrict__ x, const float* __restrict__ emb,
                           u16* __restrict__ Y) {
  const int row = blockIdx.x;
  const int tok = x[row];
  const float4 v = ((const float4*)(emb + (size_t)tok * H))[threadIdx.x];
  ushort4 o;
  o.x = f2bf(v.x); o.y = f2bf(v.y); o.z = f2bf(v.z); o.w = f2bf(v.w);
  *(ushort4*)(Y + (size_t)row * H + threadIdx.x * 4) = o;
}

// ---------------- grid barrier (device-scope atomics; 64 co-resident WGs) ----------------

__device__ __forceinline__ void gridbar(unsigned* __restrict__ bar, unsigned target) {
  __syncthreads();
  if (threadIdx.x == 0) {
    __threadfence();  // release my h-stores (agent scope)
    __hip_atomic_fetch_add(bar, 1u, __ATOMIC_RELAXED, __HIP_MEMORY_SCOPE_AGENT);
    while (__hip_atomic_load(bar, __ATOMIC_RELAXED, __HIP_MEMORY_SCOPE_AGENT) < target)
      __builtin_amdgcn_s_sleep(1);
    __threadfence();  // acquire side
  }
  __syncthreads();
}

// ---------------- LSTM scan: one layer, persistent, 64 WGs x 256 thr ----------------
// WG w owns j in [16w,16w+16). Wave wid owns j-subrange; lane (b=lane&15, lg=lane>>4)
// owns exactly one (b, j=16w+4*wid+lg): all 4 gates land in its 4 acc regs; c stays in reg.
// z = Wih@x_t + Whh@h_{t-1} + bias via mfma_16x16x32 (A = weight slice, B = x/h).

__global__ __launch_bounds__(256, 1) void lstm_scan(
    const u16* __restrict__ Yin, u16* __restrict__ Yout,
    const u16* __restrict__ Wih, const u16* __restrict__ Whh,
    const float* __restrict__ bias, const u16* __restrict__ h0b,
    const float* __restrict__ c0, float* __restrict__ hfin, float* __restrict__ cfin,
    unsigned* __restrict__ bar)
{
  const int tid = threadIdx.x;
  const int lane = tid & 63;
  const int wid = tid >> 6;
  const int b = lane & 15;
  const int lg = lane >> 4;
  const int jbase = blockIdx.x * 16;
  const int j = jbase + wid * 4 + lg;
  const int m = lane & 15;
  // slice row r = wid*16 + m maps to (gate = r&3, j_off = r>>2)
  const int arow = (m & 3) * H + jbase + wid * 4 + (m >> 2);

  const short8* __restrict__ wihp = (const short8*)(Wih + (size_t)arow * H + lg * 8);
  const short8* __restrict__ whhp = (const short8*)(Whh + (size_t)arow * H + lg * 8);

  f32x4 bias4;
  bias4[0] = bias[0 * H + j];
  bias4[1] = bias[1 * H + j];
  bias4[2] = bias[2 * H + j];
  bias4[3] = bias[3 * H + j];

  float c = c0[b * H + j];
  const int boff = b * H + lg * 8;

  for (int t = 0; t < SEQ; ++t) {
    const u16* xb = Yin + (size_t)t * NB * H + boff;
    const u16* hb = (t == 0 ? h0b : Yout + (size_t)(t - 1) * NB * H) + boff;

    f32x4 a0 = bias4;
    f32x4 a1 = {0.f, 0.f, 0.f, 0.f};
    f32x4 a2 = {0.f, 0.f, 0.f, 0.f};
    f32x4 a3 = {0.f, 0.f, 0.f, 0.f};
    #pragma unroll 4
    for (int ks = 0; ks < 32; ks += 2) {
      a0 = mfma16(wihp[ks * 4],       *(const short8*)(xb + ks * 32),       a0);
      a1 = mfma16(whhp[ks * 4],       *(const short8*)(hb + ks * 32),       a1);
      a2 = mfma16(wihp[(ks + 1) * 4], *(const short8*)(xb + (ks + 1) * 32), a2);
      a3 = mfma16(whhp[(ks + 1) * 4], *(const short8*)(hb + (ks + 1) * 32), a3);
    }
    f32x4 z4 = (a0 + a1) + (a2 + a3);

    const float ig = sigm(z4[0]);
    const float fg = sigm(z4[1]);
    const float gg = tanhfast(z4[2]);
    const float og = sigm(z4[3]);
    c = fg * c + ig * gg;
    const float h = og * tanhfast(c);

    Yout[((size_t)t * NB + b) * H + j] = f2bf(h);
    if (t == SEQ - 1) {
      hfin[b * H + j] = h;
      cfin[b * H + j] = c;
    }
    if (t + 1 < SEQ) gridbar(bar, 64u * (unsigned)(t + 1));
  }
}

// ---------------- bf16 GEMM C = A @ B^T + bias (m97-style 128x128 tile) ----------------
// A [M,1024] bf16, Bw [N,1024] bf16, C [M,N] f32. grid.x = m-tile, grid.y = n-tile.

__global__ __launch_bounds__(256, 1) void gemm_bt_bias(
    const u16* __restrict__ A, const u16* __restrict__ Bw,
    const float* __restrict__ bias, float* __restrict__ C, int N)
{
  __shared__ u16 As[128 * 64];
  __shared__ u16 Bs[128 * 64];
  const int tid = threadIdx.x;
  const int lane = tid & 63;
  const int wid = tid >> 6;
  const int m0 = blockIdx.x * 128;
  const int n0 = blockIdx.y * 128;
  const int wr = wid >> 1, wc = wid & 1;
  const int lr = lane >> 3;
  const int lc = (lane & 7) * 8;
  f32x4 acc[4][4] = {};

  for (int k0 = 0; k0 < H; k0 += 64) {
    __syncthreads();
    #pragma unroll
    for (int cc = 0; cc < 4; ++cc) {
      const int row = wid * 32 + cc * 8 + lr;
      __builtin_amdgcn_global_load_lds(
          (const __attribute__((address_space(1))) void*)(A + (size_t)(m0 + row) * H + k0 + lc),
          (__attribute__((address_space(3))) void*)(As + row * 64 + lc), 16, 0, 0);
      __builtin_amdgcn_global_load_lds(
          (const __attribute__((address_space(1))) void*)(Bw + (size_t)(n0 + row) * H + k0 + lc),
          (__attribute__((address_space(3))) void*)(Bs + row * 64 + lc), 16, 0, 0);
    }
    __syncthreads();
    #pragma unroll
    for (int ks = 0; ks < 2; ++ks) {
      short8 af[4], bfr[4];
      #pragma unroll
      for (int i = 0; i < 4; ++i) {
        af[i]  = *(const short8*)&As[(wr * 64 + i * 16 + (lane & 15)) * 64 + ks * 32 + (lane >> 4) * 8];
        bfr[i] = *(const short8*)&Bs[(wc * 64 + i * 16 + (lane & 15)) * 64 + ks * 32 + (lane >> 4) * 8];
      }
      #pragma unroll
      for (int i = 0; i < 4; ++i) {
        #pragma unroll
        for (int jj = 0; jj < 4; ++jj)
          acc[i][jj] = mfma16(af[i], bfr[jj], acc[i][jj]);
      }
    }
  }

  #pragma unroll
  for (int jj = 0; jj < 4; ++jj) {
    const int col = n0 + wc * 64 + jj * 16 + (lane & 15);
    const float bv = bias[col];
    #pragma unroll
    for (int i = 0; i < 4; ++i) {
      const int rbase = m0 + wr * 64 + i * 16 + (lane >> 4) * 4;
      #pragma unroll
      for (int r = 0; r < 4; ++r)
        C[(size_t)(rbase + r) * N + col] = acc[i][jj][r] + bv;
    }
  }
}

// ---------------- launch ----------------

extern "C" void kernel_launch(void* const* d_in, const int* in_sizes, int n_in,
                              void* d_out, int out_size, void* d_ws, size_t ws_size,
                              hipStream_t stream) {
  const int*   x    = (const int*)d_in[0];
  const float* h0   = (const float*)d_in[1];
  const float* c0   = (const float*)d_in[2];
  const float* emb  = (const float*)d_in[3];
  const float* W_ih = (const float*)d_in[4];
  const float* W_hh = (const float*)d_in[5];
  const float* b_ih = (const float*)d_in[6];
  const float* b_hh = (const float*)d_in[7];
  const float* fc_W = (const float*)d_in[8];
  const float* fc_b = (const float*)d_in[9];
  float* out = (float*)d_out;
  char* ws = (char*)d_ws;

  size_t off = 0;
  u16* WihB = (u16*)(ws + off); off += (size_t)NL * G4 * H * 2;     // 33,554,432
  u16* WhhB = (u16*)(ws + off); off += (size_t)NL * G4 * H * 2;     // 33,554,432
  u16* fcWB = (u16*)(ws + off); off += (size_t)VOCAB * H * 2;       // 65,536,000
  u16* h0B  = (u16*)(ws + off); off += (size_t)NL * NB * H * 2;     // 131,072
  float* biasB = (float*)(ws + off); off += (size_t)NL * G4 * 4;    // 65,536
  u16* YA = (u16*)(ws + off); off += (size_t)SEQ * NB * H * 2;      // 8,388,608
  u16* YB = (u16*)(ws + off); off += (size_t)SEQ * NB * H * 2;      // 8,388,608
  unsigned* bars = (unsigned*)(ws + off); off += 256;
  if (ws_size < off) return;  // fail loudly (output stays invalid) rather than corrupt

  int n8;
  n8 = NL * G4 * H / 8;  cvt_bf16<<<(n8 + 255) / 256, 256, 0, stream>>>(W_ih, WihB, n8);
  n8 = NL * G4 * H / 8;  cvt_bf16<<<(n8 + 255) / 256, 256, 0, stream>>>(W_hh, WhhB, n8);
  n8 = VOCAB * H / 8;    cvt_bf16<<<(n8 + 255) / 256, 256, 0, stream>>>(fc_W, fcWB, n8);
  n8 = NL * NB * H / 8;  cvt_bf16<<<(n8 + 255) / 256, 256, 0, stream>>>(h0, h0B, n8);
  bias_sum<<<(NL * G4 + 255) / 256, 256, 0, stream>>>(b_ih, b_hh, biasB, NL * G4);
  zero_u32<<<1, 64, 0, stream>>>(bars, NL);
  gather_emb<<<SEQ * NB, 256, 0, stream>>>(x, emb, YA);

  float* hfin = out + (size_t)SEQ * NB * VOCAB;
  float* cfin = hfin + (size_t)NL * NB * H;

  u16* Yi = YA;
  u16* Yo = YB;
  for (int l = 0; l < NL; ++l) {
    lstm_scan<<<64, 256, 0, stream>>>(
        Yi, Yo,
        WihB + (size_t)l * G4 * H, WhhB + (size_t)l * G4 * H,
        biasB + (size_t)l * G4, h0B + (size_t)l * NB * H,
        c0 + (size_t)l * NB * H,
        hfin + (size_t)l * NB * H, cfin + (size_t)l * NB * H,
        bars + l);
    u16* tmp = Yi; Yi = Yo; Yo = tmp;
  }

  gemm_bt_bias<<<dim3(32, 250), 256, 0, stream>>>(Yi, fcWB, fc_b, out, VOCAB);
}

// Round 2
// 11623.103 us; speedup vs baseline: 1.9525x; 1.9525x over previous
//
#include <hip/hip_runtime.h>
#include <hip/hip_bf16.h>

typedef unsigned short u16;
typedef short short8 __attribute__((ext_vector_type(8)));
typedef u16 u16x8 __attribute__((ext_vector_type(8)));
typedef float f32x4 __attribute__((ext_vector_type(4)));

#define H 1024
#define NB 16
#define SEQ 256
#define NL 4
#define VOCAB 32000
#define G4 4096
#define YSZ ((size_t)SEQ * NB * H)

__device__ __forceinline__ u16 f2bf(float f) {
  __hip_bfloat16 h = __float2bfloat16(f);
  return *reinterpret_cast<u16*>(&h);
}
__device__ __forceinline__ float sigm(float x) { return 1.0f / (1.0f + __expf(-x)); }
__device__ __forceinline__ float tanhfast(float x) { return 2.0f / (1.0f + __expf(-2.0f * x)) - 1.0f; }

__device__ __forceinline__ f32x4 mfma16(short8 a, short8 b, f32x4 c) {
  return __builtin_amdgcn_mfma_f32_16x16x32_bf16(a, b, c, 0, 0, 0);
}

// ---------------- small prep kernels ----------------

__global__ void cvt_bf16(const float* __restrict__ in, u16* __restrict__ out, int n8) {
  const int i = blockIdx.x * blockDim.x + threadIdx.x;
  if (i >= n8) return;
  const float4 a = ((const float4*)in)[2 * i];
  const float4 b = ((const float4*)in)[2 * i + 1];
  u16x8 o;
  o[0] = f2bf(a.x); o[1] = f2bf(a.y); o[2] = f2bf(a.z); o[3] = f2bf(a.w);
  o[4] = f2bf(b.x); o[5] = f2bf(b.y); o[6] = f2bf(b.z); o[7] = f2bf(b.w);
  *(u16x8*)(out + (size_t)i * 8) = o;
}

__global__ void bias_sum(const float* __restrict__ a, const float* __restrict__ b,
                         float* __restrict__ o, int n) {
  const int i = blockIdx.x * blockDim.x + threadIdx.x;
  if (i < n) o[i] = a[i] + b[i];
}

__global__ void zero_u32(unsigned* __restrict__ p, int n) {
  const int i = blockIdx.x * blockDim.x + threadIdx.x;
  if (i < n) p[i] = 0u;
}

__global__ void gather_emb(const int* __restrict__ x, const float* __restrict__ emb,
                           u16* __restrict__ Y) {
  const int row = blockIdx.x;
  const int tok = x[row];
  const float4 v = ((const float4*)(emb + (size_t)tok * H))[threadIdx.x];
  ushort4 o;
  o.x = f2bf(v.x); o.y = f2bf(v.y); o.z = f2bf(v.z); o.w = f2bf(v.w);
  *(ushort4*)(Y + (size_t)row * H + threadIdx.x * 4) = o;
}

// ---------------- WG-level wait on a device counter ----------------
// Only thread 0 polls (single fabric transaction stream); other waves park on
// the hardware barrier. Acquire fence by all threads after release.

__device__ __forceinline__ void wg_waitge(const unsigned* __restrict__ p, unsigned target) {
  if (threadIdx.x == 0) {
    while (__hip_atomic_load(p, __ATOMIC_RELAXED, __HIP_MEMORY_SCOPE_AGENT) < target)
      __builtin_amdgcn_s_sleep(1);
  }
  __syncthreads();
  __threadfence();
}

// ---------------- LSTM: 4-layer wavefront pipeline, 256 WGs x 256 thr ----------------
// blockIdx = l*64 + jgrp. WG owns j in [16*jgrp, 16*jgrp+16) of layer l.
// Whh slice (64 rows x 1024, 128 KB) lives in LDS (XOR-swizzled).
// Per step: [wait x from layer l-1] -> Zx = Wih@x_t (global, overlaps waits)
//           -> [wait own h barrier] -> += Whh@h (LDS A-frags) -> gates -> store -> signal.

__global__ __launch_bounds__(256, 1) void lstm_scan(
    const u16* __restrict__ ybase_r, u16* __restrict__ ybase_w,
    const u16* __restrict__ Wih_all, const u16* __restrict__ Whh_all,
    const float* __restrict__ bias_all, const u16* __restrict__ h0_all,
    const float* __restrict__ c0_all, float* __restrict__ hfin_all,
    float* __restrict__ cfin_all, unsigned* __restrict__ bars)
{
  extern __shared__ u16 sm[];  // 64 rows x 1024 u16 = 128 KiB, swizzled
  const int tid = threadIdx.x;
  const int lane = tid & 63;
  const int wid = tid >> 6;
  const int l = blockIdx.x >> 6;
  const int jgrp = blockIdx.x & 63;
  const int jbase = jgrp * 16;
  const int b = lane & 15;
  const int lg = lane >> 4;
  const int m = lane & 15;
  const int j = jbase + wid * 4 + lg;

  const u16* __restrict__ Yin  = ybase_r + (size_t)l * YSZ;
  u16* __restrict__ Yout       = ybase_w + (size_t)(l + 1) * YSZ;
  const u16* __restrict__ Wih  = Wih_all + (size_t)l * G4 * H;
  const u16* __restrict__ Whh  = Whh_all + (size_t)l * G4 * H;
  const float* __restrict__ bias = bias_all + (size_t)l * G4;
  const u16* __restrict__ h0b  = h0_all + (size_t)l * NB * H;
  const float* __restrict__ c0 = c0_all + (size_t)l * NB * H;
  float* __restrict__ hfin     = hfin_all + (size_t)l * NB * H;
  float* __restrict__ cfin     = cfin_all + (size_t)l * NB * H;
  unsigned* __restrict__ mybar = bars + l * 32;          // 128 B apart
  const unsigned* __restrict__ xbar = bars + (l - 1) * 32;

  // ---- stage Whh slice into LDS (once, swizzled: col ^= v(row)*8) ----
  {
    const int r = tid >> 2, q = tid & 3;          // r: local row 0..63, q: col quarter
    const int gate = r >> 4, jloc = r & 15;
    const unsigned v8 = (unsigned)((gate * 4 + (jloc & 3)) * 8);
    const u16* src = Whh + ((size_t)gate * H + (jbase + jloc)) * H + q * 256;
    u16* dstrow = sm + r * 1024;
    #pragma unroll
    for (int i = 0; i < 32; ++i) {
      u16x8 w = *(const u16x8*)(src + i * 8);
      *(u16x8*)(dstrow + (((unsigned)(q * 256 + i * 8)) ^ v8)) = w;
    }
  }
  __syncthreads();

  // A-fragment addressing (same lane->row map as verified round-0 kernel)
  const short8* __restrict__ wihp =
      (const short8*)(Wih + (size_t)((m & 3) * H + jbase + wid * 4 + (m >> 2)) * H + lg * 8);
  const int rloc = (m & 3) * 16 + wid * 4 + (m >> 2);
  const unsigned v8r = (unsigned)(((m & 3) * 4 + (m >> 2)) * 8);
  const u16* __restrict__ smrow = sm + rloc * 1024;

  f32x4 bias4;
  bias4[0] = bias[0 * H + j];
  bias4[1] = bias[1 * H + j];
  bias4[2] = bias[2 * H + j];
  bias4[3] = bias[3 * H + j];

  float c = c0[b * H + j];
  const int boff = b * H + lg * 8;

  for (int t = 0; t < SEQ; ++t) {
    // x_t ready? (layer l-1 finished its step t)
    if (l > 0) wg_waitge(xbar, 64u * (unsigned)(t + 1));
    const u16* xb = Yin + (size_t)t * (NB * H) + boff;

    f32x4 a0 = bias4;
    f32x4 a1 = {0.f, 0.f, 0.f, 0.f};
    f32x4 a2 = {0.f, 0.f, 0.f, 0.f};
    f32x4 a3 = {0.f, 0.f, 0.f, 0.f};

    // Zx = Wih @ x_t : stream from L2, 16 loads in flight per block
    #pragma unroll
    for (int kb = 0; kb < 4; ++kb) {
      short8 wa[8], xv[8];
      #pragma unroll
      for (int i = 0; i < 8; ++i) {
        wa[i] = wihp[(kb * 8 + i) * 4];
        xv[i] = *(const short8*)(xb + (kb * 8 + i) * 32);
      }
      a0 = mfma16(wa[0], xv[0], a0); a1 = mfma16(wa[1], xv[1], a1);
      a2 = mfma16(wa[2], xv[2], a2); a3 = mfma16(wa[3], xv[3], a3);
      a0 = mfma16(wa[4], xv[4], a0); a1 = mfma16(wa[5], xv[5], a1);
      a2 = mfma16(wa[6], xv[6], a2); a3 = mfma16(wa[7], xv[7], a3);
    }

    // h_{t-1} ready? (own layer's previous step, all 64 WGs)
    if (t > 0) wg_waitge(mybar, 64u * (unsigned)t);
    const u16* hb = (t == 0 ? h0b : Yout + (size_t)(t - 1) * (NB * H)) + boff;

    // += Whh @ h : A-frags from LDS (swizzled), B-frags from global
    #pragma unroll
    for (int kb = 0; kb < 4; ++kb) {
      short8 hv[8], ha[8];
      #pragma unroll
      for (int i = 0; i < 8; ++i)
        hv[i] = *(const short8*)(hb + (kb * 8 + i) * 32);
      #pragma unroll
      for (int i = 0; i < 8; ++i) {
        const unsigned col = ((unsigned)(lg * 8 + (kb * 8 + i) * 32)) ^ v8r;
        ha[i] = *(const short8*)(smrow + col);
      }
      a0 = mfma16(ha[0], hv[0], a0); a1 = mfma16(ha[1], hv[1], a1);
      a2 = mfma16(ha[2], hv[2], a2); a3 = mfma16(ha[3], hv[3], a3);
      a0 = mfma16(ha[4], hv[4], a0); a1 = mfma16(ha[5], hv[5], a1);
      a2 = mfma16(ha[6], hv[6], a2); a3 = mfma16(ha[7], hv[7], a3);
    }

    f32x4 z4 = (a0 + a1) + (a2 + a3);
    const float ig = sigm(z4[0]);
    const float fg = sigm(z4[1]);
    const float gg = tanhfast(z4[2]);
    const float og = sigm(z4[3]);
    c = fg * c + ig * gg;
    const float h = og * tanhfast(c);

    Yout[((size_t)t * NB + b) * H + j] = f2bf(h);
    if (t == SEQ - 1) {
      hfin[b * H + j] = h;
      cfin[b * H + j] = c;
    }

    // arrival: __syncthreads drains vmcnt per wave; release fence + add by tid 0
    __syncthreads();
    if (tid == 0) {
      __threadfence();
      __hip_atomic_fetch_add(mybar, 1u, __ATOMIC_RELAXED, __HIP_MEMORY_SCOPE_AGENT);
    }
  }
}

// ---------------- bf16 GEMM C = A @ Bw^T + bias; Bw is f32, converted in staging ----------------

__global__ __launch_bounds__(256, 1) void gemm_bt_bias(
    const u16* __restrict__ A, const float* __restrict__ Bw,
    const float* __restrict__ bias, float* __restrict__ C, int N)
{
  __shared__ u16 As[128 * 64];
  __shared__ u16 Bs[128 * 64];
  const int tid = threadIdx.x;
  const int lane = tid & 63;
  const int wid = tid >> 6;
  const int m0 = blockIdx.x * 128;
  const int n0 = blockIdx.y * 128;
  const int wr = wid >> 1, wc = wid & 1;
  const int lr = lane >> 3;
  const int lc = (lane & 7) * 8;
  f32x4 acc[4][4] = {};

  for (int k0 = 0; k0 < H; k0 += 64) {
    __syncthreads();
    #pragma unroll
    for (int cc = 0; cc < 4; ++cc) {
      const int row = wid * 32 + cc * 8 + lr;
      __builtin_amdgcn_global_load_lds(
          (const __attribute__((address_space(1))) void*)(A + (size_t)(m0 + row) * H + k0 + lc),
          (__attribute__((address_space(3))) void*)(As + row * 64 + lc), 16, 0, 0);
      const float* bsrc = Bw + (size_t)(n0 + row) * H + k0 + lc;
      const float4 f0 = *(const float4*)bsrc;
      const float4 f1 = *(const float4*)(bsrc + 4);
      u16x8 o;
      o[0] = f2bf(f0.x); o[1] = f2bf(f0.y); o[2] = f2bf(f0.z); o[3] = f2bf(f0.w);
      o[4] = f2bf(f1.x); o[5] = f2bf(f1.y); o[6] = f2bf(f1.z); o[7] = f2bf(f1.w);
      *(u16x8*)&Bs[row * 64 + lc] = o;
    }
    __syncthreads();
    #pragma unroll
    for (int ks = 0; ks < 2; ++ks) {
      short8 af[4], bfr[4];
      #pragma unroll
      for (int i = 0; i < 4; ++i) {
        af[i]  = *(const short8*)&As[(wr * 64 + i * 16 + (lane & 15)) * 64 + ks * 32 + (lane >> 4) * 8];
        bfr[i] = *(const short8*)&Bs[(wc * 64 + i * 16 + (lane & 15)) * 64 + ks * 32 + (lane >> 4) * 8];
      }
      #pragma unroll
      for (int i = 0; i < 4; ++i) {
        #pragma unroll
        for (int jj = 0; jj < 4; ++jj)
          acc[i][jj] = mfma16(af[i], bfr[jj], acc[i][jj]);
      }
    }
  }

  #pragma unroll
  for (int jj = 0; jj < 4; ++jj) {
    const int col = n0 + wc * 64 + jj * 16 + (lane & 15);
    const float bv = bias[col];
    #pragma unroll
    for (int i = 0; i < 4; ++i) {
      const int rbase = m0 + wr * 64 + i * 16 + (lane >> 4) * 4;
      #pragma unroll
      for (int r = 0; r < 4; ++r)
        C[(size_t)(rbase + r) * N + col] = acc[i][jj][r] + bv;
    }
  }
}

// ---------------- launch ----------------

extern "C" void kernel_launch(void* const* d_in, const int* in_sizes, int n_in,
                              void* d_out, int out_size, void* d_ws, size_t ws_size,
                              hipStream_t stream) {
  const int*   x    = (const int*)d_in[0];
  const float* h0   = (const float*)d_in[1];
  const float* c0   = (const float*)d_in[2];
  const float* emb  = (const float*)d_in[3];
  const float* W_ih = (const float*)d_in[4];
  const float* W_hh = (const float*)d_in[5];
  const float* b_ih = (const float*)d_in[6];
  const float* b_hh = (const float*)d_in[7];
  const float* fc_W = (const float*)d_in[8];
  const float* fc_b = (const float*)d_in[9];
  float* out = (float*)d_out;
  char* ws = (char*)d_ws;

  size_t off = 0;
  u16* WihB = (u16*)(ws + off); off += (size_t)NL * G4 * H * 2;   // 33.6 MB
  u16* WhhB = (u16*)(ws + off); off += (size_t)NL * G4 * H * 2;   // 33.6 MB
  u16* h0B  = (u16*)(ws + off); off += (size_t)NL * NB * H * 2;
  float* biasB = (float*)(ws + off); off += (size_t)NL * G4 * 4;
  u16* ybufs = (u16*)(ws + off); off += (size_t)(NL + 1) * YSZ * 2;  // 41.9 MB
  unsigned* bars = (unsigned*)(ws + off); off += 512;
  if (ws_size < off) return;  // fail loudly rather than corrupt

  int n8;
  n8 = NL * G4 * H / 8;  cvt_bf16<<<(n8 + 255) / 256, 256, 0, stream>>>(W_ih, WihB, n8);
  n8 = NL * G4 * H / 8;  cvt_bf16<<<(n8 + 255) / 256, 256, 0, stream>>>(W_hh, WhhB, n8);
  n8 = NL * NB * H / 8;  cvt_bf16<<<(n8 + 255) / 256, 256, 0, stream>>>(h0, h0B, n8);
  bias_sum<<<(NL * G4 + 255) / 256, 256, 0, stream>>>(b_ih, b_hh, biasB, NL * G4);
  zero_u32<<<1, 128, 0, stream>>>(bars, 128);
  gather_emb<<<SEQ * NB, 256, 0, stream>>>(x, emb, ybufs);

  float* hfin = out + (size_t)SEQ * NB * VOCAB;
  float* cfin = hfin + (size_t)NL * NB * H;

  lstm_scan<<<NL * 64, 256, 131072, stream>>>(
      ybufs, ybufs, WihB, WhhB, biasB, h0B, c0, hfin, cfin, bars);

  gemm_bt_bias<<<dim3(32, 250), 256, 0, stream>>>(
      ybufs + (size_t)NL * YSZ, fc_W, fc_b, out, VOCAB);
}

// Round 3
// 10799.499 us; speedup vs baseline: 2.1014x; 1.0763x over previous
//
#include <hip/hip_runtime.h>
#include <hip/hip_bf16.h>

typedef unsigned short u16;
typedef short short8 __attribute__((ext_vector_type(8)));
typedef u16 u16x8 __attribute__((ext_vector_type(8)));
typedef float f32x4 __attribute__((ext_vector_type(4)));

#define H 1024
#define NB 16
#define SEQ 256
#define NL 4
#define VOCAB 32000
#define G4 4096
#define YSZ ((size_t)SEQ * NB * H)

__device__ __forceinline__ u16 f2bf(float f) {
  __hip_bfloat16 h = __float2bfloat16(f);
  return *reinterpret_cast<u16*>(&h);
}
__device__ __forceinline__ float sigm(float x) { return 1.0f / (1.0f + __expf(-x)); }
__device__ __forceinline__ float tanhfast(float x) { return 2.0f / (1.0f + __expf(-2.0f * x)) - 1.0f; }

__device__ __forceinline__ f32x4 mfma16(short8 a, short8 b, f32x4 c) {
  return __builtin_amdgcn_mfma_f32_16x16x32_bf16(a, b, c, 0, 0, 0);
}

// ---------------- small prep kernels ----------------

__global__ void cvt_bf16(const float* __restrict__ in, u16* __restrict__ out, int n8) {
  const int i = blockIdx.x * blockDim.x + threadIdx.x;
  if (i >= n8) return;
  const float4 a = ((const float4*)in)[2 * i];
  const float4 b = ((const float4*)in)[2 * i + 1];
  u16x8 o;
  o[0] = f2bf(a.x); o[1] = f2bf(a.y); o[2] = f2bf(a.z); o[3] = f2bf(a.w);
  o[4] = f2bf(b.x); o[5] = f2bf(b.y); o[6] = f2bf(b.z); o[7] = f2bf(b.w);
  *(u16x8*)(out + (size_t)i * 8) = o;
}

__global__ void bias_sum(const float* __restrict__ a, const float* __restrict__ b,
                         float* __restrict__ o, int n) {
  const int i = blockIdx.x * blockDim.x + threadIdx.x;
  if (i < n) o[i] = a[i] + b[i];
}

__global__ void zero_u32(unsigned* __restrict__ p, int n) {
  const int i = blockIdx.x * blockDim.x + threadIdx.x;
  if (i < n) p[i] = 0u;
}

__global__ void gather_emb(const int* __restrict__ x, const float* __restrict__ emb,
                           u16* __restrict__ Y) {
  const int row = blockIdx.x;
  const int tok = x[row];
  const float4 v = ((const float4*)(emb + (size_t)tok * H))[threadIdx.x];
  ushort4 o;
  o.x = f2bf(v.x); o.y = f2bf(v.y); o.z = f2bf(v.z); o.w = f2bf(v.w);
  *(ushort4*)(Y + (size_t)row * H + threadIdx.x * 4) = o;
}

// ---------------- WG wait on device counter (tid0 polls, rest park) ----------------

__device__ __forceinline__ void wgwait(const unsigned* __restrict__ p, unsigned target) {
  if (threadIdx.x == 0) {
    while (__hip_atomic_load(p, __ATOMIC_RELAXED, __HIP_MEMORY_SCOPE_AGENT) < target)
      __builtin_amdgcn_s_sleep(2);
  }
  __syncthreads();
  __threadfence();  // acquire: invalidate stale L1/L2 before reading x/h
}

// 8 loads (next batch) + 8 MFMAs (current batch). All W indices compile-time.
#define BATCH(W, base, CUR, NXT, nxtp)                        \
  do {                                                        \
    _Pragma("unroll")                                         \
    for (int i_ = 0; i_ < 8; ++i_)                            \
      NXT[i_] = *(const short8*)((nxtp) + i_ * 32);           \
    a0 = mfma16(W[(base) + 0], CUR[0], a0);                   \
    a1 = mfma16(W[(base) + 1], CUR[1], a1);                   \
    a2 = mfma16(W[(base) + 2], CUR[2], a2);                   \
    a3 = mfma16(W[(base) + 3], CUR[3], a3);                   \
    a0 = mfma16(W[(base) + 4], CUR[4], a0);                   \
    a1 = mfma16(W[(base) + 5], CUR[5], a1);                   \
    a2 = mfma16(W[(base) + 6], CUR[6], a2);                   \
    a3 = mfma16(W[(base) + 7], CUR[7], a3);                   \
  } while (0)

#define BATCH_LAST(W, base, CUR)                              \
  do {                                                        \
    a0 = mfma16(W[(base) + 0], CUR[0], a0);                   \
    a1 = mfma16(W[(base) + 1], CUR[1], a1);                   \
    a2 = mfma16(W[(base) + 2], CUR[2], a2);                   \
    a3 = mfma16(W[(base) + 3], CUR[3], a3);                   \
    a0 = mfma16(W[(base) + 4], CUR[4], a0);                   \
    a1 = mfma16(W[(base) + 5], CUR[5], a1);                   \
    a2 = mfma16(W[(base) + 6], CUR[6], a2);                   \
    a3 = mfma16(W[(base) + 7], CUR[7], a3);                   \
  } while (0)

// ---------------- LSTM: 4-layer wavefront pipeline, weights in VGPRs ----------------
// 256 WGs x 256 thr (1 WG/CU, 1 wave/SIMD). blockIdx = l*64 + jgrp.
// Wave owns 4 j's; Wih+Whh A-frags (256 VGPRs) resident across all 256 steps.
// Per step only x_t/h_{t-1} B-frags (64 KB/WG) move through the MALL.

__global__ __launch_bounds__(256, 1) void lstm_scan(
    const u16* __restrict__ ybase_r, u16* __restrict__ ybase_w,
    const u16* __restrict__ Wih_all, const u16* __restrict__ Whh_all,
    const float* __restrict__ bias_all, const u16* __restrict__ h0_all,
    const float* __restrict__ c0_all, float* __restrict__ hfin_all,
    float* __restrict__ cfin_all, unsigned* __restrict__ bars)
{
  const int tid = threadIdx.x;
  const int lane = tid & 63;
  const int wid = tid >> 6;
  const int l = blockIdx.x >> 6;
  const int jgrp = blockIdx.x & 63;
  const int jbase = jgrp * 16;
  const int b = lane & 15;
  const int lg = lane >> 4;
  const int m = lane & 15;
  const int j = jbase + wid * 4 + lg;

  const u16* __restrict__ Yin  = ybase_r + (size_t)l * YSZ;
  u16* __restrict__ Yout       = ybase_w + (size_t)(l + 1) * YSZ;
  const u16* __restrict__ Wih  = Wih_all + (size_t)l * G4 * H;
  const u16* __restrict__ Whh  = Whh_all + (size_t)l * G4 * H;
  const float* __restrict__ bias = bias_all + (size_t)l * G4;
  const u16* __restrict__ h0b  = h0_all + (size_t)l * NB * H;
  const float* __restrict__ c0 = c0_all + (size_t)l * NB * H;
  float* __restrict__ hfin     = hfin_all + (size_t)l * NB * H;
  float* __restrict__ cfin     = cfin_all + (size_t)l * NB * H;
  unsigned* __restrict__ mybar = bars + l * 256;          // 1 KiB apart
  const unsigned* __restrict__ xbar = bars + (l - 1) * 256;

  // ---- weights -> registers (verified round-0/2 fragment mapping) ----
  const size_t arow = (size_t)((m & 3) * H + jbase + wid * 4 + (m >> 2));
  const short8* __restrict__ wihp = (const short8*)(Wih + arow * H + lg * 8);
  const short8* __restrict__ whhp = (const short8*)(Whh + arow * H + lg * 8);
  short8 WI[32], WH[32];
  #pragma unroll
  for (int ks = 0; ks < 32; ++ks) WI[ks] = wihp[ks * 4];
  #pragma unroll
  for (int ks = 0; ks < 32; ++ks) WH[ks] = whhp[ks * 4];

  f32x4 bias4;
  bias4[0] = bias[0 * H + j];
  bias4[1] = bias[1 * H + j];
  bias4[2] = bias[2 * H + j];
  bias4[3] = bias[3 * H + j];

  float c = c0[b * H + j];
  const int boff = b * H + lg * 8;

  for (int t = 0; t < SEQ; ++t) {
    // x_t ready? (layer l-1 finished step t). Binding wait in steady state.
    if (l > 0) wgwait(xbar, 64u * (unsigned)(t + 1));
    const u16* xb = Yin + (size_t)t * (NB * H) + boff;

    f32x4 a0 = bias4;
    f32x4 a1 = {0.f, 0.f, 0.f, 0.f};
    f32x4 a2 = {0.f, 0.f, 0.f, 0.f};
    f32x4 a3 = {0.f, 0.f, 0.f, 0.f};

    short8 fA[8], fB[8];
    #pragma unroll
    for (int i_ = 0; i_ < 8; ++i_) fA[i_] = *(const short8*)(xb + i_ * 32);
    BATCH(WI, 0,  fA, fB, xb + 8 * 32);
    BATCH(WI, 8,  fB, fA, xb + 16 * 32);
    BATCH(WI, 16, fA, fB, xb + 24 * 32);

    // own h_{t-1} ready? (usually already satisfied; overlaps x-phase)
    if (t > 0) wgwait(mybar, 64u * (unsigned)t);
    const u16* hb = (t == 0 ? h0b : Yout + (size_t)(t - 1) * (NB * H)) + boff;

    BATCH(WI, 24, fB, fA, hb);
    BATCH(WH, 0,  fA, fB, hb + 8 * 32);
    BATCH(WH, 8,  fB, fA, hb + 16 * 32);
    BATCH(WH, 16, fA, fB, hb + 24 * 32);
    BATCH_LAST(WH, 24, fB);

    f32x4 z4 = (a0 + a1) + (a2 + a3);
    const float ig = sigm(z4[0]);
    const float fg = sigm(z4[1]);
    const float gg = tanhfast(z4[2]);
    const float og = sigm(z4[3]);
    c = fg * c + ig * gg;
    const float h = og * tanhfast(c);

    Yout[((size_t)t * NB + b) * H + j] = f2bf(h);
    if (t == SEQ - 1) {
      hfin[b * H + j] = h;
      cfin[b * H + j] = c;
    }

    // arrival: syncthreads drains each wave's vmcnt; tid0 releases + signals
    __syncthreads();
    if (tid == 0) {
      __threadfence();
      __hip_atomic_fetch_add(mybar, 1u, __ATOMIC_RELAXED, __HIP_MEMORY_SCOPE_AGENT);
    }
  }
}

// ---------------- bf16 GEMM C = A @ Bw^T + bias (both operands bf16, gload_lds) ----------------

__global__ __launch_bounds__(256, 1) void gemm_bt_bias(
    const u16* __restrict__ A, const u16* __restrict__ Bw,
    const float* __restrict__ bias, float* __restrict__ C, int N)
{
  __shared__ u16 As[128 * 64];
  __shared__ u16 Bs[128 * 64];
  const int tid = threadIdx.x;
  const int lane = tid & 63;
  const int wid = tid >> 6;
  const int m0 = blockIdx.x * 128;
  const int n0 = blockIdx.y * 128;
  const int wr = wid >> 1, wc = wid & 1;
  const int lr = lane >> 3;
  const int lc = (lane & 7) * 8;
  f32x4 acc[4][4] = {};

  for (int k0 = 0; k0 < H; k0 += 64) {
    __syncthreads();
    #pragma unroll
    for (int cc = 0; cc < 4; ++cc) {
      const int row = wid * 32 + cc * 8 + lr;
      __builtin_amdgcn_global_load_lds(
          (const __attribute__((address_space(1))) void*)(A + (size_t)(m0 + row) * H + k0 + lc),
          (__attribute__((address_space(3))) void*)(As + row * 64 + lc), 16, 0, 0);
      __builtin_amdgcn_global_load_lds(
          (const __attribute__((address_space(1))) void*)(Bw + (size_t)(n0 + row) * H + k0 + lc),
          (__attribute__((address_space(3))) void*)(Bs + row * 64 + lc), 16, 0, 0);
    }
    __syncthreads();
    #pragma unroll
    for (int ks = 0; ks < 2; ++ks) {
      short8 af[4], bfr[4];
      #pragma unroll
      for (int i = 0; i < 4; ++i) {
        af[i]  = *(const short8*)&As[(wr * 64 + i * 16 + (lane & 15)) * 64 + ks * 32 + (lane >> 4) * 8];
        bfr[i] = *(const short8*)&Bs[(wc * 64 + i * 16 + (lane & 15)) * 64 + ks * 32 + (lane >> 4) * 8];
      }
      #pragma unroll
      for (int i = 0; i < 4; ++i) {
        #pragma unroll
        for (int jj = 0; jj < 4; ++jj)
          acc[i][jj] = mfma16(af[i], bfr[jj], acc[i][jj]);
      }
    }
  }

  #pragma unroll
  for (int jj = 0; jj < 4; ++jj) {
    const int col = n0 + wc * 64 + jj * 16 + (lane & 15);
    const float bv = bias[col];
    #pragma unroll
    for (int i = 0; i < 4; ++i) {
      const int rbase = m0 + wr * 64 + i * 16 + (lane >> 4) * 4;
      #pragma unroll
      for (int r = 0; r < 4; ++r)
        C[(size_t)(rbase + r) * N + col] = acc[i][jj][r] + bv;
    }
  }
}

// ---------------- launch ----------------

extern "C" void kernel_launch(void* const* d_in, const int* in_sizes, int n_in,
                              void* d_out, int out_size, void* d_ws, size_t ws_size,
                              hipStream_t stream) {
  const int*   x    = (const int*)d_in[0];
  const float* h0   = (const float*)d_in[1];
  const float* c0   = (const float*)d_in[2];
  const float* emb  = (const float*)d_in[3];
  const float* W_ih = (const float*)d_in[4];
  const float* W_hh = (const float*)d_in[5];
  const float* b_ih = (const float*)d_in[6];
  const float* b_hh = (const float*)d_in[7];
  const float* fc_W = (const float*)d_in[8];
  const float* fc_b = (const float*)d_in[9];
  float* out = (float*)d_out;
  char* ws = (char*)d_ws;

  size_t off = 0;
  u16* WihB = (u16*)(ws + off); off += (size_t)NL * G4 * H * 2;   // 33.6 MB
  u16* WhhB = (u16*)(ws + off); off += (size_t)NL * G4 * H * 2;   // 33.6 MB
  u16* fcWB = (u16*)(ws + off); off += (size_t)VOCAB * H * 2;     // 65.5 MB
  u16* h0B  = (u16*)(ws + off); off += (size_t)NL * NB * H * 2;
  float* biasB = (float*)(ws + off); off += (size_t)NL * G4 * 4;
  u16* ybufs = (u16*)(ws + off); off += (size_t)(NL + 1) * YSZ * 2;  // 41.9 MB
  unsigned* bars = (unsigned*)(ws + off); off += 4096;
  if (ws_size < off) return;  // fail loudly rather than corrupt

  int n8;
  n8 = NL * G4 * H / 8;  cvt_bf16<<<(n8 + 255) / 256, 256, 0, stream>>>(W_ih, WihB, n8);
  n8 = NL * G4 * H / 8;  cvt_bf16<<<(n8 + 255) / 256, 256, 0, stream>>>(W_hh, WhhB, n8);
  n8 = VOCAB * H / 8;    cvt_bf16<<<(n8 + 255) / 256, 256, 0, stream>>>(fc_W, fcWB, n8);
  n8 = NL * NB * H / 8;  cvt_bf16<<<(n8 + 255) / 256, 256, 0, stream>>>(h0, h0B, n8);
  bias_sum<<<(NL * G4 + 255) / 256, 256, 0, stream>>>(b_ih, b_hh, biasB, NL * G4);
  zero_u32<<<4, 256, 0, stream>>>(bars, 1024);
  gather_emb<<<SEQ * NB, 256, 0, stream>>>(x, emb, ybufs);

  float* hfin = out + (size_t)SEQ * NB * VOCAB;
  float* cfin = hfin + (size_t)NL * NB * H;

  lstm_scan<<<NL * 64, 256, 0, stream>>>(
      ybufs, ybufs, WihB, WhhB, biasB, h0B, c0, hfin, cfin, bars);

  gemm_bt_bias<<<dim3(32, 250), 256, 0, stream>>>(
      ybufs + (size_t)NL * YSZ, fcWB, fc_b, out, VOCAB);
}

// Round 4
// 10798.100 us; speedup vs baseline: 2.1017x; 1.0001x over previous
//
#include <hip/hip_runtime.h>
#include <hip/hip_bf16.h>

typedef unsigned short u16;
typedef short short8 __attribute__((ext_vector_type(8)));
typedef u16 u16x8 __attribute__((ext_vector_type(8)));
typedef float f32x4 __attribute__((ext_vector_type(4)));

#define H 1024
#define NB 16
#define SEQ 256
#define NL 4
#define VOCAB 32000
#define G4 4096
#define YSZ ((size_t)SEQ * NB * H)

__device__ __forceinline__ u16 f2bf(float f) {
  __hip_bfloat16 h = __float2bfloat16(f);
  return *reinterpret_cast<u16*>(&h);
}
__device__ __forceinline__ float sigm(float x) { return 1.0f / (1.0f + __expf(-x)); }
__device__ __forceinline__ float tanhfast(float x) { return 2.0f / (1.0f + __expf(-2.0f * x)) - 1.0f; }

__device__ __forceinline__ f32x4 mfma16(short8 a, short8 b, f32x4 c) {
  return __builtin_amdgcn_mfma_f32_16x16x32_bf16(a, b, c, 0, 0, 0);
}

// ---------------- small prep kernels ----------------

__global__ void cvt_bf16(const float* __restrict__ in, u16* __restrict__ out, int n8) {
  const int i = blockIdx.x * blockDim.x + threadIdx.x;
  if (i >= n8) return;
  const float4 a = ((const float4*)in)[2 * i];
  const float4 b = ((const float4*)in)[2 * i + 1];
  u16x8 o;
  o[0] = f2bf(a.x); o[1] = f2bf(a.y); o[2] = f2bf(a.z); o[3] = f2bf(a.w);
  o[4] = f2bf(b.x); o[5] = f2bf(b.y); o[6] = f2bf(b.z); o[7] = f2bf(b.w);
  *(u16x8*)(out + (size_t)i * 8) = o;
}

__global__ void bias_sum(const float* __restrict__ a, const float* __restrict__ b,
                         float* __restrict__ o, int n) {
  const int i = blockIdx.x * blockDim.x + threadIdx.x;
  if (i < n) o[i] = a[i] + b[i];
}

__global__ void zero_u32(unsigned* __restrict__ p, int n) {
  const int i = blockIdx.x * blockDim.x + threadIdx.x;
  if (i < n) p[i] = 0u;
}

__global__ void gather_emb(const int* __restrict__ x, const float* __restrict__ emb,
                           u16* __restrict__ Y) {
  const int row = blockIdx.x;
  const int tok = x[row];
  const float4 v = ((const float4*)(emb + (size_t)tok * H))[threadIdx.x];
  ushort4 o;
  o.x = f2bf(v.x); o.y = f2bf(v.y); o.z = f2bf(v.z); o.w = f2bf(v.w);
  *(ushort4*)(Y + (size_t)row * H + threadIdx.x * 4) = o;
}

// ---------------- WG wait on device counter (tid0 polls, rest park) ----------------

__device__ __forceinline__ void wgwait(const unsigned* __restrict__ p, unsigned target) {
  if (threadIdx.x == 0) {
    while (__hip_atomic_load(p, __ATOMIC_RELAXED, __HIP_MEMORY_SCOPE_AGENT) < target)
      __builtin_amdgcn_s_sleep(2);
  }
  __syncthreads();
  __threadfence();  // acquire: invalidate stale L1/L2 before reading x/h
}

// 8 loads (next batch) + 8 MFMAs (current batch). All W indices compile-time.
#define BATCH(W, base, CUR, NXT, nxtp)                        \
  do {                                                        \
    _Pragma("unroll")                                         \
    for (int i_ = 0; i_ < 8; ++i_)                            \
      NXT[i_] = *(const short8*)((nxtp) + i_ * 32);           \
    a0 = mfma16(W[(base) + 0], CUR[0], a0);                   \
    a1 = mfma16(W[(base) + 1], CUR[1], a1);                   \
    a2 = mfma16(W[(base) + 2], CUR[2], a2);                   \
    a3 = mfma16(W[(base) + 3], CUR[3], a3);                   \
    a0 = mfma16(W[(base) + 4], CUR[4], a0);                   \
    a1 = mfma16(W[(base) + 5], CUR[5], a1);                   \
    a2 = mfma16(W[(base) + 6], CUR[6], a2);                   \
    a3 = mfma16(W[(base) + 7], CUR[7], a3);                   \
  } while (0)

#define BATCH_LAST(W, base, CUR)                              \
  do {                                                        \
    a0 = mfma16(W[(base) + 0], CUR[0], a0);                   \
    a1 = mfma16(W[(base) + 1], CUR[1], a1);                   \
    a2 = mfma16(W[(base) + 2], CUR[2], a2);                   \
    a3 = mfma16(W[(base) + 3], CUR[3], a3);                   \
    a0 = mfma16(W[(base) + 4], CUR[4], a0);                   \
    a1 = mfma16(W[(base) + 5], CUR[5], a1);                   \
    a2 = mfma16(W[(base) + 6], CUR[6], a2);                   \
    a3 = mfma16(W[(base) + 7], CUR[7], a3);                   \
  } while (0)

// ---------------- LSTM: 4-layer wavefront pipeline, weights in VGPRs ----------------
// 256 WGs x 256 thr (1 WG/CU, 1 wave/SIMD). blockIdx = l*64 + jgrp.
// Wave owns 4 j's; Wih+Whh A-frags (256 VGPRs) resident across all 256 steps.
// Per step only x_t/h_{t-1} B-frags (64 KB/WG) move through the MALL.

__global__ __launch_bounds__(256, 1) void lstm_scan(
    const u16* __restrict__ ybase_r, u16* __restrict__ ybase_w,
    const u16* __restrict__ Wih_all, const u16* __restrict__ Whh_all,
    const float* __restrict__ bias_all, const u16* __restrict__ h0_all,
    const float* __restrict__ c0_all, float* __restrict__ hfin_all,
    float* __restrict__ cfin_all, unsigned* __restrict__ bars)
{
  const int tid = threadIdx.x;
  const int lane = tid & 63;
  const int wid = tid >> 6;
  const int l = blockIdx.x >> 6;
  const int jgrp = blockIdx.x & 63;
  const int jbase = jgrp * 16;
  const int b = lane & 15;
  const int lg = lane >> 4;
  const int m = lane & 15;
  const int j = jbase + wid * 4 + lg;

  const u16* __restrict__ Yin  = ybase_r + (size_t)l * YSZ;
  u16* __restrict__ Yout       = ybase_w + (size_t)(l + 1) * YSZ;
  const u16* __restrict__ Wih  = Wih_all + (size_t)l * G4 * H;
  const u16* __restrict__ Whh  = Whh_all + (size_t)l * G4 * H;
  const float* __restrict__ bias = bias_all + (size_t)l * G4;
  const u16* __restrict__ h0b  = h0_all + (size_t)l * NB * H;
  const float* __restrict__ c0 = c0_all + (size_t)l * NB * H;
  float* __restrict__ hfin     = hfin_all + (size_t)l * NB * H;
  float* __restrict__ cfin     = cfin_all + (size_t)l * NB * H;
  unsigned* __restrict__ mybar = bars + l * 256;          // 1 KiB apart
  const unsigned* __restrict__ xbar = bars + (l - 1) * 256;

  // ---- weights -> registers (verified round-0/2 fragment mapping) ----
  const size_t arow = (size_t)((m & 3) * H + jbase + wid * 4 + (m >> 2));
  const short8* __restrict__ wihp = (const short8*)(Wih + arow * H + lg * 8);
  const short8* __restrict__ whhp = (const short8*)(Whh + arow * H + lg * 8);
  short8 WI[32], WH[32];
  #pragma unroll
  for (int ks = 0; ks < 32; ++ks) WI[ks] = wihp[ks * 4];
  #pragma unroll
  for (int ks = 0; ks < 32; ++ks) WH[ks] = whhp[ks * 4];

  f32x4 bias4;
  bias4[0] = bias[0 * H + j];
  bias4[1] = bias[1 * H + j];
  bias4[2] = bias[2 * H + j];
  bias4[3] = bias[3 * H + j];

  float c = c0[b * H + j];
  const int boff = b * H + lg * 8;

  for (int t = 0; t < SEQ; ++t) {
    // x_t ready? (layer l-1 finished step t). Binding wait in steady state.
    if (l > 0) wgwait(xbar, 64u * (unsigned)(t + 1));
    const u16* xb = Yin + (size_t)t * (NB * H) + boff;

    f32x4 a0 = bias4;
    f32x4 a1 = {0.f, 0.f, 0.f, 0.f};
    f32x4 a2 = {0.f, 0.f, 0.f, 0.f};
    f32x4 a3 = {0.f, 0.f, 0.f, 0.f};

    short8 fA[8], fB[8];
    #pragma unroll
    for (int i_ = 0; i_ < 8; ++i_) fA[i_] = *(const short8*)(xb + i_ * 32);
    BATCH(WI, 0,  fA, fB, xb + 8 * 32);
    BATCH(WI, 8,  fB, fA, xb + 16 * 32);
    BATCH(WI, 16, fA, fB, xb + 24 * 32);

    // own h_{t-1} ready? (usually already satisfied; overlaps x-phase)
    if (t > 0) wgwait(mybar, 64u * (unsigned)t);
    const u16* hb = (t == 0 ? h0b : Yout + (size_t)(t - 1) * (NB * H)) + boff;

    BATCH(WI, 24, fB, fA, hb);
    BATCH(WH, 0,  fA, fB, hb + 8 * 32);
    BATCH(WH, 8,  fB, fA, hb + 16 * 32);
    BATCH(WH, 16, fA, fB, hb + 24 * 32);
    BATCH_LAST(WH, 24, fB);

    f32x4 z4 = (a0 + a1) + (a2 + a3);
    const float ig = sigm(z4[0]);
    const float fg = sigm(z4[1]);
    const float gg = tanhfast(z4[2]);
    const float og = sigm(z4[3]);
    c = fg * c + ig * gg;
    const float h = og * tanhfast(c);

    Yout[((size_t)t * NB + b) * H + j] = f2bf(h);
    if (t == SEQ - 1) {
      hfin[b * H + j] = h;
      cfin[b * H + j] = c;
    }

    // arrival: syncthreads drains each wave's vmcnt; tid0 releases + signals
    __syncthreads();
    if (tid == 0) {
      __threadfence();
      __hip_atomic_fetch_add(mybar, 1u, __ATOMIC_RELAXED, __HIP_MEMORY_SCOPE_AGENT);
    }
  }
}

// ---------------- bf16 GEMM C = A @ Bw^T + bias (both operands bf16, gload_lds) ----------------

__global__ __launch_bounds__(256, 1) void gemm_bt_bias(
    const u16* __restrict__ A, const u16* __restrict__ Bw,
    const float* __restrict__ bias, float* __restrict__ C, int N)
{
  __shared__ u16 As[128 * 64];
  __shared__ u16 Bs[128 * 64];
  const int tid = threadIdx.x;
  const int lane = tid & 63;
  const int wid = tid >> 6;
  const int m0 = blockIdx.x * 128;
  const int n0 = blockIdx.y * 128;
  const int wr = wid >> 1, wc = wid & 1;
  const int lr = lane >> 3;
  const int lc = (lane & 7) * 8;
  f32x4 acc[4][4] = {};

  for (int k0 = 0; k0 < H; k0 += 64) {
    __syncthreads();
    #pragma unroll
    for (int cc = 0; cc < 4; ++cc) {
      const int row = wid * 32 + cc * 8 + lr;
      __builtin_amdgcn_global_load_lds(
          (const __attribute__((address_space(1))) void*)(A + (size_t)(m0 + row) * H + k0 + lc),
          (__attribute__((address_space(3))) void*)(As + row * 64 + lc), 16, 0, 0);
      __builtin_amdgcn_global_load_lds(
          (const __attribute__((address_space(1))) void*)(Bw + (size_t)(n0 + row) * H + k0 + lc),
          (__attribute__((address_space(3))) void*)(Bs + row * 64 + lc), 16, 0, 0);
    }
    __syncthreads();
    #pragma unroll
    for (int ks = 0; ks < 2; ++ks) {
      short8 af[4], bfr[4];
      #pragma unroll
      for (int i = 0; i < 4; ++i) {
        af[i]  = *(const short8*)&As[(wr * 64 + i * 16 + (lane & 15)) * 64 + ks * 32 + (lane >> 4) * 8];
        bfr[i] = *(const short8*)&Bs[(wc * 64 + i * 16 + (lane & 15)) * 64 + ks * 32 + (lane >> 4) * 8];
      }
      #pragma unroll
      for (int i = 0; i < 4; ++i) {
        #pragma unroll
        for (int jj = 0; jj < 4; ++jj)
          acc[i][jj] = mfma16(af[i], bfr[jj], acc[i][jj]);
      }
    }
  }

  #pragma unroll
  for (int jj = 0; jj < 4; ++jj) {
    const int col = n0 + wc * 64 + jj * 16 + (lane & 15);
    const float bv = bias[col];
    #pragma unroll
    for (int i = 0; i < 4; ++i) {
      const int rbase = m0 + wr * 64 + i * 16 + (lane >> 4) * 4;
      #pragma unroll
      for (int r = 0; r < 4; ++r)
        C[(size_t)(rbase + r) * N + col] = acc[i][jj][r] + bv;
    }
  }
}

// ---------------- launch ----------------

extern "C" void kernel_launch(void* const* d_in, const int* in_sizes, int n_in,
                              void* d_out, int out_size, void* d_ws, size_t ws_size,
                              hipStream_t stream) {
  const int*   x    = (const int*)d_in[0];
  const float* h0   = (const float*)d_in[1];
  const float* c0   = (const float*)d_in[2];
  const float* emb  = (const float*)d_in[3];
  const float* W_ih = (const float*)d_in[4];
  const float* W_hh = (const float*)d_in[5];
  const float* b_ih = (const float*)d_in[6];
  const float* b_hh = (const float*)d_in[7];
  const float* fc_W = (const float*)d_in[8];
  const float* fc_b = (const float*)d_in[9];
  float* out = (float*)d_out;
  char* ws = (char*)d_ws;

  size_t off = 0;
  u16* WihB = (u16*)(ws + off); off += (size_t)NL * G4 * H * 2;   // 33.6 MB
  u16* WhhB = (u16*)(ws + off); off += (size_t)NL * G4 * H * 2;   // 33.6 MB
  u16* fcWB = (u16*)(ws + off); off += (size_t)VOCAB * H * 2;     // 65.5 MB
  u16* h0B  = (u16*)(ws + off); off += (size_t)NL * NB * H * 2;
  float* biasB = (float*)(ws + off); off += (size_t)NL * G4 * 4;
  u16* ybufs = (u16*)(ws + off); off += (size_t)(NL + 1) * YSZ * 2;  // 41.9 MB
  unsigned* bars = (unsigned*)(ws + off); off += 4096;
  if (ws_size < off) return;  // fail loudly rather than corrupt

  int n8;
  n8 = NL * G4 * H / 8;  cvt_bf16<<<(n8 + 255) / 256, 256, 0, stream>>>(W_ih, WihB, n8);
  n8 = NL * G4 * H / 8;  cvt_bf16<<<(n8 + 255) / 256, 256, 0, stream>>>(W_hh, WhhB, n8);
  n8 = VOCAB * H / 8;    cvt_bf16<<<(n8 + 255) / 256, 256, 0, stream>>>(fc_W, fcWB, n8);
  n8 = NL * NB * H / 8;  cvt_bf16<<<(n8 + 255) / 256, 256, 0, stream>>>(h0, h0B, n8);
  bias_sum<<<(NL * G4 + 255) / 256, 256, 0, stream>>>(b_ih, b_hh, biasB, NL * G4);
  zero_u32<<<4, 256, 0, stream>>>(bars, 1024);
  gather_emb<<<SEQ * NB, 256, 0, stream>>>(x, emb, ybufs);

  float* hfin = out + (size_t)SEQ * NB * VOCAB;
  float* cfin = hfin + (size_t)NL * NB * H;

  lstm_scan<<<NL * 64, 256, 0, stream>>>(
      ybufs, ybufs, WihB, WhhB, biasB, h0B, c0, hfin, cfin, bars);

  gemm_bt_bias<<<dim3(32, 250), 256, 0, stream>>>(
      ybufs + (size_t)NL * YSZ, fcWB, fc_b, out, VOCAB);
}

// Round 5
// 2913.122 us; speedup vs baseline: 7.7903x; 3.7067x over previous
//
#include <hip/hip_runtime.h>
#include <hip/hip_bf16.h>

typedef unsigned short u16;
typedef short short8 __attribute__((ext_vector_type(8)));
typedef u16 u16x8 __attribute__((ext_vector_type(8)));
typedef float f32x4 __attribute__((ext_vector_type(4)));

#define H 1024
#define NB 16
#define SEQ 256
#define NL 4
#define VOCAB 32000
#define G4 4096
#define YSZ ((size_t)SEQ * NB * H)

__device__ __forceinline__ u16 f2bf(float f) {
  __hip_bfloat16 h = __float2bfloat16(f);
  return *reinterpret_cast<u16*>(&h);
}
__device__ __forceinline__ float sigm(float x) { return 1.0f / (1.0f + __expf(-x)); }
__device__ __forceinline__ float tanhfast(float x) { return 2.0f / (1.0f + __expf(-2.0f * x)) - 1.0f; }

__device__ __forceinline__ f32x4 mfma16(short8 a, short8 b, f32x4 c) {
  return __builtin_amdgcn_mfma_f32_16x16x32_bf16(a, b, c, 0, 0, 0);
}

// Device-coherent 16B load: bypass L1, read at MALL coherence point (no fences needed).
template <int BOFF>
__device__ __forceinline__ short8 ldg_sc(const u16* p) {
  short8 r;
  asm volatile("global_load_dwordx4 %0, %1, off offset:%2 sc0 sc1"
               : "=&v"(r) : "v"(p), "n"(BOFF));
  return r;
}

#define WAITV(N)                                               \
  do {                                                         \
    asm volatile("s_waitcnt vmcnt(" #N ")" ::: "memory");      \
    __builtin_amdgcn_sched_barrier(0);                         \
  } while (0)

#define LD1(d, p, I) d[(I) & 15] = ldg_sc<(I) * 64>(p)
#define ISSUE16(d, p, B0)                                                      \
  do {                                                                         \
    LD1(d, p, (B0) + 0);  LD1(d, p, (B0) + 1);  LD1(d, p, (B0) + 2);           \
    LD1(d, p, (B0) + 3);  LD1(d, p, (B0) + 4);  LD1(d, p, (B0) + 5);           \
    LD1(d, p, (B0) + 6);  LD1(d, p, (B0) + 7);  LD1(d, p, (B0) + 8);           \
    LD1(d, p, (B0) + 9);  LD1(d, p, (B0) + 10); LD1(d, p, (B0) + 11);          \
    LD1(d, p, (B0) + 12); LD1(d, p, (B0) + 13); LD1(d, p, (B0) + 14);          \
    LD1(d, p, (B0) + 15);                                                      \
  } while (0)

#define MM16(W, wb, F)                                                         \
  do {                                                                         \
    a0 = mfma16(W[(wb) + 0],  F[0],  a0); a1 = mfma16(W[(wb) + 1],  F[1],  a1);\
    a2 = mfma16(W[(wb) + 2],  F[2],  a2); a3 = mfma16(W[(wb) + 3],  F[3],  a3);\
    a0 = mfma16(W[(wb) + 4],  F[4],  a0); a1 = mfma16(W[(wb) + 5],  F[5],  a1);\
    a2 = mfma16(W[(wb) + 6],  F[6],  a2); a3 = mfma16(W[(wb) + 7],  F[7],  a3);\
    a0 = mfma16(W[(wb) + 8],  F[8],  a0); a1 = mfma16(W[(wb) + 9],  F[9],  a1);\
    a2 = mfma16(W[(wb) + 10], F[10], a2); a3 = mfma16(W[(wb) + 11], F[11], a3);\
    a0 = mfma16(W[(wb) + 12], F[12], a0); a1 = mfma16(W[(wb) + 13], F[13], a1);\
    a2 = mfma16(W[(wb) + 14], F[14], a2); a3 = mfma16(W[(wb) + 15], F[15], a3);\
  } while (0)

// ---------------- small prep kernels ----------------

__global__ void cvt_bf16(const float* __restrict__ in, u16* __restrict__ out, int n8) {
  const int i = blockIdx.x * blockDim.x + threadIdx.x;
  if (i >= n8) return;
  const float4 a = ((const float4*)in)[2 * i];
  const float4 b = ((const float4*)in)[2 * i + 1];
  u16x8 o;
  o[0] = f2bf(a.x); o[1] = f2bf(a.y); o[2] = f2bf(a.z); o[3] = f2bf(a.w);
  o[4] = f2bf(b.x); o[5] = f2bf(b.y); o[6] = f2bf(b.z); o[7] = f2bf(b.w);
  *(u16x8*)(out + (size_t)i * 8) = o;
}

__global__ void bias_sum(const float* __restrict__ a, const float* __restrict__ b,
                         float* __restrict__ o, int n) {
  const int i = blockIdx.x * blockDim.x + threadIdx.x;
  if (i < n) o[i] = a[i] + b[i];
}

__global__ void zero_u32(unsigned* __restrict__ p, int n) {
  const int i = blockIdx.x * blockDim.x + threadIdx.x;
  if (i < n) p[i] = 0u;
}

__global__ void gather_emb(const int* __restrict__ x, const float* __restrict__ emb,
                           u16* __restrict__ Y) {
  const int row = blockIdx.x;
  const int tok = x[row];
  const float4 v = ((const float4*)(emb + (size_t)tok * H))[threadIdx.x];
  ushort4 o;
  o.x = f2bf(v.x); o.y = f2bf(v.y); o.z = f2bf(v.z); o.w = f2bf(v.w);
  *(ushort4*)(Y + (size_t)row * H + threadIdx.x * 4) = o;
}

__device__ __forceinline__ void poll_ge(const unsigned* __restrict__ p, unsigned target) {
  while (__hip_atomic_load(p, __ATOMIC_RELAXED, __HIP_MEMORY_SCOPE_AGENT) < target)
    __builtin_amdgcn_s_sleep(1);
}

// ---------------- LSTM: 4-layer wavefront pipeline, no cache-wide fences ----------------
// 256 WGs x 256 thr (1 WG/CU). blockIdx = l*64 + jgrp; wave owns 4 j-columns.
// Weights pinned in VGPRs (asm-touched so they can't be rematerialized).
// Cross-WG h/x exchange via sc0sc1 (device-coherent) loads/stores at the MALL;
// signals via relaxed agent atomics. L1/L2 are never invalidated -> stay hot.

__global__ __launch_bounds__(256, 1) void lstm_scan(
    const u16* __restrict__ ybase_r, u16* __restrict__ ybase_w,
    const u16* __restrict__ Wih_all, const u16* __restrict__ Whh_all,
    const float* __restrict__ bias_all, const u16* __restrict__ h0_all,
    const float* __restrict__ c0_all, float* __restrict__ hfin_all,
    float* __restrict__ cfin_all, unsigned* __restrict__ bars)
{
  __shared__ u16 smh[NB * 16];  // [b][jloc] h-tile for coalesced publish
  const int tid = threadIdx.x;
  const int lane = tid & 63;
  const int wid = tid >> 6;
  const int l = blockIdx.x >> 6;
  const int jgrp = blockIdx.x & 63;
  const int jbase = jgrp * 16;
  const int b = lane & 15;
  const int lg = lane >> 4;
  const int m = lane & 15;
  const int j = jbase + wid * 4 + lg;

  const u16* __restrict__ Yin  = ybase_r + (size_t)l * YSZ;
  u16* __restrict__ Yout       = ybase_w + (size_t)(l + 1) * YSZ;
  const u16* __restrict__ Wih  = Wih_all + (size_t)l * G4 * H;
  const u16* __restrict__ Whh  = Whh_all + (size_t)l * G4 * H;
  const float* __restrict__ bias = bias_all + (size_t)l * G4;
  const u16* __restrict__ h0b  = h0_all + (size_t)l * NB * H;
  const float* __restrict__ c0 = c0_all + (size_t)l * NB * H;
  float* __restrict__ hfin     = hfin_all + (size_t)l * NB * H;
  float* __restrict__ cfin     = cfin_all + (size_t)l * NB * H;
  unsigned* __restrict__ mybar = bars + l * 256;           // 1 KiB apart
  const unsigned* __restrict__ xbar = bars + (l - 1) * 256;

  // ---- weights -> VGPRs (verified fragment map), pinned against remat ----
  const size_t arow = (size_t)((m & 3) * H + jbase + wid * 4 + (m >> 2));
  const short8* __restrict__ wihp = (const short8*)(Wih + arow * H + lg * 8);
  const short8* __restrict__ whhp = (const short8*)(Whh + arow * H + lg * 8);
  short8 WI[32], WH[32];
  #pragma unroll
  for (int ks = 0; ks < 32; ++ks) WI[ks] = wihp[ks * 4];
  #pragma unroll
  for (int ks = 0; ks < 32; ++ks) WH[ks] = whhp[ks * 4];
  #pragma unroll
  for (int ks = 0; ks < 32; ++ks) {
    asm volatile("" : "+v"(WI[ks]));
    asm volatile("" : "+v"(WH[ks]));
  }

  f32x4 bias4;
  bias4[0] = bias[0 * H + j];
  bias4[1] = bias[1 * H + j];
  bias4[2] = bias[2 * H + j];
  bias4[3] = bias[3 * H + j];

  float c = c0[b * H + j];
  const int boff = b * H + lg * 8;

  for (int t = 0; t < SEQ; ++t) {
    // x_t ready? (layer l-1 finished step t)
    if (l > 0) {
      if (tid == 0) poll_ge(xbar, 64u * (unsigned)(t + 1));
      __syncthreads();
    }
    const u16* xb = Yin + (size_t)t * (NB * H) + boff;

    f32x4 a0 = bias4;
    f32x4 a1 = {0.f, 0.f, 0.f, 0.f};
    f32x4 a2 = {0.f, 0.f, 0.f, 0.f};
    f32x4 a3 = {0.f, 0.f, 0.f, 0.f};

    short8 fA[16], fB[16];
    ISSUE16(fA, xb, 0);
    ISSUE16(fB, xb, 16);
    WAITV(16);
    MM16(WI, 0, fA);

    // own h_{t-1} ready?
    if (t > 0) {
      if (tid == 0) poll_ge(mybar, 64u * (unsigned)t);
      __syncthreads();
    }
    const u16* hb = (t == 0 ? h0b : Yout + (size_t)(t - 1) * (NB * H)) + boff;

    ISSUE16(fA, hb, 0);     // hA reuses fA regs
    WAITV(16);
    MM16(WI, 16, fB);
    ISSUE16(fB, hb, 16);    // hB reuses fB regs
    WAITV(16);
    MM16(WH, 0, fA);
    WAITV(0);
    MM16(WH, 16, fB);

    f32x4 z4 = (a0 + a1) + (a2 + a3);
    const float ig = sigm(z4[0]);
    const float fg = sigm(z4[1]);
    const float gg = tanhfast(z4[2]);
    const float og = sigm(z4[3]);
    c = fg * c + ig * gg;
    const float h = og * tanhfast(c);

    smh[b * 16 + wid * 4 + lg] = f2bf(h);
    if (t == SEQ - 1) {
      hfin[b * H + j] = h;
      cfin[b * H + j] = c;
    }

    __syncthreads();  // smh complete
    if (wid == 0) {
      if (lane < 32) {
        const int br = lane >> 1, half = lane & 1;
        u16x8 pv = *(const u16x8*)&smh[br * 16 + half * 8];
        const u16* dst = Yout + (size_t)t * (NB * H) + (size_t)br * H + jbase + half * 8;
        asm volatile("global_store_dwordx4 %0, %1, off sc0 sc1"
                     :: "v"(dst), "v"(pv) : "memory");
      }
      asm volatile("s_waitcnt vmcnt(0)" ::: "memory");  // stores at coherence point
      if (lane == 0)
        __hip_atomic_fetch_add(mybar, 1u, __ATOMIC_RELAXED, __HIP_MEMORY_SCOPE_AGENT);
    }
  }
}

// ---------------- bf16 GEMM C = A @ Bw^T + bias (round-0 proven) ----------------

__global__ __launch_bounds__(256, 1) void gemm_bt_bias(
    const u16* __restrict__ A, const u16* __restrict__ Bw,
    const float* __restrict__ bias, float* __restrict__ C, int N)
{
  __shared__ u16 As[128 * 64];
  __shared__ u16 Bs[128 * 64];
  const int tid = threadIdx.x;
  const int lane = tid & 63;
  const int wid = tid >> 6;
  const int m0 = blockIdx.x * 128;
  const int n0 = blockIdx.y * 128;
  const int wr = wid >> 1, wc = wid & 1;
  const int lr = lane >> 3;
  const int lc = (lane & 7) * 8;
  f32x4 acc[4][4] = {};

  for (int k0 = 0; k0 < H; k0 += 64) {
    __syncthreads();
    #pragma unroll
    for (int cc = 0; cc < 4; ++cc) {
      const int row = wid * 32 + cc * 8 + lr;
      __builtin_amdgcn_global_load_lds(
          (const __attribute__((address_space(1))) void*)(A + (size_t)(m0 + row) * H + k0 + lc),
          (__attribute__((address_space(3))) void*)(As + row * 64 + lc), 16, 0, 0);
      __builtin_amdgcn_global_load_lds(
          (const __attribute__((address_space(1))) void*)(Bw + (size_t)(n0 + row) * H + k0 + lc),
          (__attribute__((address_space(3))) void*)(Bs + row * 64 + lc), 16, 0, 0);
    }
    __syncthreads();
    #pragma unroll
    for (int ks = 0; ks < 2; ++ks) {
      short8 af[4], bfr[4];
      #pragma unroll
      for (int i = 0; i < 4; ++i) {
        af[i]  = *(const short8*)&As[(wr * 64 + i * 16 + (lane & 15)) * 64 + ks * 32 + (lane >> 4) * 8];
        bfr[i] = *(const short8*)&Bs[(wc * 64 + i * 16 + (lane & 15)) * 64 + ks * 32 + (lane >> 4) * 8];
      }
      #pragma unroll
      for (int i = 0; i < 4; ++i) {
        #pragma unroll
        for (int jj = 0; jj < 4; ++jj)
          acc[i][jj] = mfma16(af[i], bfr[jj], acc[i][jj]);
      }
    }
  }

  #pragma unroll
  for (int jj = 0; jj < 4; ++jj) {
    const int col = n0 + wc * 64 + jj * 16 + (lane & 15);
    const float bv = bias[col];
    #pragma unroll
    for (int i = 0; i < 4; ++i) {
      const int rbase = m0 + wr * 64 + i * 16 + (lane >> 4) * 4;
      #pragma unroll
      for (int r = 0; r < 4; ++r)
        C[(size_t)(rbase + r) * N + col] = acc[i][jj][r] + bv;
    }
  }
}

// ---------------- launch ----------------

extern "C" void kernel_launch(void* const* d_in, const int* in_sizes, int n_in,
                              void* d_out, int out_size, void* d_ws, size_t ws_size,
                              hipStream_t stream) {
  const int*   x    = (const int*)d_in[0];
  const float* h0   = (const float*)d_in[1];
  const float* c0   = (const float*)d_in[2];
  const float* emb  = (const float*)d_in[3];
  const float* W_ih = (const float*)d_in[4];
  const float* W_hh = (const float*)d_in[5];
  const float* b_ih = (const float*)d_in[6];
  const float* b_hh = (const float*)d_in[7];
  const float* fc_W = (const float*)d_in[8];
  const float* fc_b = (const float*)d_in[9];
  float* out = (float*)d_out;
  char* ws = (char*)d_ws;

  size_t off = 0;
  u16* WihB = (u16*)(ws + off); off += (size_t)NL * G4 * H * 2;   // 33.6 MB
  u16* WhhB = (u16*)(ws + off); off += (size_t)NL * G4 * H * 2;   // 33.6 MB
  u16* fcWB = (u16*)(ws + off); off += (size_t)VOCAB * H * 2;     // 65.5 MB
  u16* h0B  = (u16*)(ws + off); off += (size_t)NL * NB * H * 2;
  float* biasB = (float*)(ws + off); off += (size_t)NL * G4 * 4;
  u16* ybufs = (u16*)(ws + off); off += (size_t)(NL + 1) * YSZ * 2;  // 41.9 MB
  unsigned* bars = (unsigned*)(ws + off); off += 4096;
  if (ws_size < off) return;  // fail loudly rather than corrupt

  int n8;
  n8 = NL * G4 * H / 8;  cvt_bf16<<<(n8 + 255) / 256, 256, 0, stream>>>(W_ih, WihB, n8);
  n8 = NL * G4 * H / 8;  cvt_bf16<<<(n8 + 255) / 256, 256, 0, stream>>>(W_hh, WhhB, n8);
  n8 = VOCAB * H / 8;    cvt_bf16<<<(n8 + 255) / 256, 256, 0, stream>>>(fc_W, fcWB, n8);
  n8 = NL * NB * H / 8;  cvt_bf16<<<(n8 + 255) / 256, 256, 0, stream>>>(h0, h0B, n8);
  bias_sum<<<(NL * G4 + 255) / 256, 256, 0, stream>>>(b_ih, b_hh, biasB, NL * G4);
  zero_u32<<<4, 256, 0, stream>>>(bars, 1024);
  gather_emb<<<SEQ * NB, 256, 0, stream>>>(x, emb, ybufs);

  float* hfin = out + (size_t)SEQ * NB * VOCAB;
  float* cfin = hfin + (size_t)NL * NB * H;

  lstm_scan<<<NL * 64, 256, 0, stream>>>(
      ybufs, ybufs, WihB, WhhB, biasB, h0B, c0, hfin, cfin, bars);

  gemm_bt_bias<<<dim3(32, 250), 256, 0, stream>>>(
      ybufs + (size_t)NL * YSZ, fcWB, fc_b, out, VOCAB);
}

// Round 7
// 1709.108 us; speedup vs baseline: 13.2784x; 1.7045x over previous
//
#include <hip/hip_runtime.h>
#include <hip/hip_bf16.h>

typedef unsigned short u16;
typedef short short8 __attribute__((ext_vector_type(8)));
typedef u16 u16x8 __attribute__((ext_vector_type(8)));
typedef float f32x4 __attribute__((ext_vector_type(4)));

#define H 1024
#define NB 16
#define SEQ 256
#define NL 4
#define VOCAB 32000
#define G4 4096
#define YSZ ((size_t)SEQ * NB * H)

__device__ __forceinline__ u16 f2bf(float f) {
  __hip_bfloat16 h = __float2bfloat16(f);
  return *reinterpret_cast<u16*>(&h);
}
__device__ __forceinline__ float sigm(float x) { return 1.0f / (1.0f + __expf(-x)); }
__device__ __forceinline__ float tanhfast(float x) { return 2.0f / (1.0f + __expf(-2.0f * x)) - 1.0f; }

__device__ __forceinline__ f32x4 mfma16(short8 a, short8 b, f32x4 c) {
  return __builtin_amdgcn_mfma_f32_16x16x32_bf16(a, b, c, 0, 0, 0);
}

// Device-coherent 16B load: bypass L1/L2, read at MALL coherence point.
template <int BOFF>
__device__ __forceinline__ short8 ldg_sc(const u16* p) {
  short8 r;
  asm volatile("global_load_dwordx4 %0, %1, off offset:%2 sc0 sc1"
               : "=&v"(r) : "v"(p), "n"(BOFF));
  return r;
}

#define WAITV0                                                 \
  do {                                                         \
    asm volatile("s_waitcnt vmcnt(0)" ::: "memory");           \
    __builtin_amdgcn_sched_barrier(0);                         \
  } while (0)

#define LD8SC(d, p)                                            \
  do {                                                         \
    d[0] = ldg_sc<0 * 64>(p); d[1] = ldg_sc<1 * 64>(p);        \
    d[2] = ldg_sc<2 * 64>(p); d[3] = ldg_sc<3 * 64>(p);        \
    d[4] = ldg_sc<4 * 64>(p); d[5] = ldg_sc<5 * 64>(p);        \
    d[6] = ldg_sc<6 * 64>(p); d[7] = ldg_sc<7 * 64>(p);        \
  } while (0)

// ---------------- small prep kernels ----------------

__global__ void cvt_bf16(const float* __restrict__ in, u16* __restrict__ out, int n8) {
  const int i = blockIdx.x * blockDim.x + threadIdx.x;
  if (i >= n8) return;
  const float4 a = ((const float4*)in)[2 * i];
  const float4 b = ((const float4*)in)[2 * i + 1];
  u16x8 o;
  o[0] = f2bf(a.x); o[1] = f2bf(a.y); o[2] = f2bf(a.z); o[3] = f2bf(a.w);
  o[4] = f2bf(b.x); o[5] = f2bf(b.y); o[6] = f2bf(b.z); o[7] = f2bf(b.w);
  *(u16x8*)(out + (size_t)i * 8) = o;
}

__global__ void bias_sum(const float* __restrict__ a, const float* __restrict__ b,
                         float* __restrict__ o, int n) {
  const int i = blockIdx.x * blockDim.x + threadIdx.x;
  if (i < n) o[i] = a[i] + b[i];
}

__global__ void zero_u32(unsigned* __restrict__ p, int n) {
  const int i = blockIdx.x * blockDim.x + threadIdx.x;
  if (i < n) p[i] = 0u;
}

__global__ void gather_emb(const int* __restrict__ x, const float* __restrict__ emb,
                           u16* __restrict__ Y) {
  const int row = blockIdx.x;
  const int tok = x[row];
  const float4 v = ((const float4*)(emb + (size_t)tok * H))[threadIdx.x];
  ushort4 o;
  o.x = f2bf(v.x); o.y = f2bf(v.y); o.z = f2bf(v.z); o.w = f2bf(v.w);
  *(ushort4*)(Y + (size_t)row * H + threadIdx.x * 4) = o;
}

// Wave-level wait: each of 64 lanes polls one WG flag (64B-spaced), ballot until all >= tgt.
__device__ __forceinline__ void wavewait(const unsigned* __restrict__ base, unsigned tgt) {
  const unsigned* p = base + (threadIdx.x & 63) * 16;
  unsigned v;
  do {
    asm volatile("global_load_dword %0, %1, off sc0 sc1\n\ts_waitcnt vmcnt(0)"
                 : "=&v"(v) : "v"(p) : "memory");
  } while (!__all(v >= tgt));
  __builtin_amdgcn_sched_barrier(0);
}

// ---------------- LSTM: 4-layer wavefront, K-split waves ----------------
// 256 WGs x 256 thr (1 WG/CU). blockIdx = l*64 + jgrp; WG owns 16 j-columns.
// Wave w owns k-steps ks in [8w, 8w+8) of ALL 64 slice rows (4 row-tiles):
//   - x/h B-frags: 8 each per wave, no cross-wave duplication (4x less MALL traffic)
//   - Wih A-frags: 32 per lane in VGPRs (128 regs, no spill pressure)
//   - Whh A-frags: LDS, fragment-ordered (conflict-free ds_read_b128)
// Per-step cross-wave partial-sum reduce via LDS. Signals: per-WG flag stores
// (sc0sc1, no atomic RMW); waits: all-lane poll + ballot. No cache-wide fences.

__global__ __launch_bounds__(256, 1) void lstm_scan(
    const u16* __restrict__ ybase_r, u16* __restrict__ ybase_w,
    const u16* __restrict__ Wih_all, const u16* __restrict__ Whh_all,
    const float* __restrict__ bias_all, const u16* __restrict__ h0_all,
    const float* __restrict__ c0_all, float* __restrict__ hfin_all,
    float* __restrict__ cfin_all, unsigned* __restrict__ bars)
{
  extern __shared__ u16 sm[];  // [0,65536): Whh frags; [65536,73728): reduce; [73728,73984): smh
  u16* __restrict__ smw = sm;
  f32x4* __restrict__ lred = (f32x4*)(sm + 65536);
  u16* __restrict__ smh = sm + 73728;

  const int tid = threadIdx.x;
  const int lane = tid & 63;
  const int wid = tid >> 6;
  const int l = blockIdx.x >> 6;
  const int jgrp = blockIdx.x & 63;
  const int jbase = jgrp * 16;
  const int b = lane & 15;
  const int lg = lane >> 4;
  const int m = lane & 15;
  const int j = jbase + wid * 4 + lg;

  const u16* __restrict__ Yin  = ybase_r + (size_t)l * YSZ;
  u16* __restrict__ Yout       = ybase_w + (size_t)(l + 1) * YSZ;
  const u16* __restrict__ Wih  = Wih_all + (size_t)l * G4 * H;
  const u16* __restrict__ Whh  = Whh_all + (size_t)l * G4 * H;
  const float* __restrict__ bias = bias_all + (size_t)l * G4;
  const u16* __restrict__ h0b  = h0_all + (size_t)l * NB * H;
  const float* __restrict__ c0 = c0_all + (size_t)l * NB * H;
  float* __restrict__ hfin     = hfin_all + (size_t)l * NB * H;
  float* __restrict__ cfin     = cfin_all + (size_t)l * NB * H;
  unsigned* __restrict__ myflags = bars + l * 1024;
  const unsigned* __restrict__ xflags = bars + (l - 1) * 1024;
  unsigned* __restrict__ myflag_wr = myflags + jgrp * 16;

  // ---- stage Whh slice into LDS, fragment-ordered (conflict-free) ----
  // (rt, ks, lane) lives at u16 offset rt*16384 + ks*512 + lane*8, ks = wid*8+i.
  #pragma unroll
  for (int rt = 0; rt < 4; ++rt) {
    const size_t ar = (size_t)((m & 3) * H + jbase + rt * 4 + (m >> 2));
    const u16* src = Whh + ar * H + lg * 8;
    #pragma unroll
    for (int i = 0; i < 8; ++i) {
      const int ks = wid * 8 + i;
      short8 w = *(const short8*)(src + ks * 32);
      *(short8*)(smw + (size_t)rt * 16384 + (size_t)ks * 512 + lane * 8) = w;
    }
  }
  // ---- Wih k-quarter -> VGPRs (128 regs) ----
  short8 WI[32];
  #pragma unroll
  for (int rt = 0; rt < 4; ++rt) {
    const size_t ar = (size_t)((m & 3) * H + jbase + rt * 4 + (m >> 2));
    const u16* src = Wih + ar * H + lg * 8;
    #pragma unroll
    for (int i = 0; i < 8; ++i) {
      WI[rt * 8 + i] = *(const short8*)(src + (wid * 8 + i) * 32);
      asm volatile("" : "+v"(WI[rt * 8 + i]));
    }
  }
  __syncthreads();

  f32x4 bias4;
  bias4[0] = bias[0 * H + j];
  bias4[1] = bias[1 * H + j];
  bias4[2] = bias[2 * H + j];
  bias4[3] = bias[3 * H + j];

  float c = c0[b * H + j];
  const int boff = b * H + lg * 8;           // per-lane column base within a [16,1024] tile
  const int kboff = wid * 256;               // wave's k-quarter offset (8 ks * 32 u16)
  // FIX (round 6 bug): wave's LDS frag base is wid*4096 u16 (ks = wid*8+i at ks*512),
  // NOT kboff*2 = wid*512 — that made waves 1..3 read the wrong k-chunks of Whh.
  const u16* __restrict__ smwv = smw + (size_t)wid * 4096 + lane * 8;  // + rt*16384 + i*512

  for (int t = 0; t < SEQ; ++t) {
    const u16* xw = Yin + (size_t)t * (NB * H) + boff + kboff;

    f32x4 a0 = {0.f, 0.f, 0.f, 0.f};
    f32x4 a1 = {0.f, 0.f, 0.f, 0.f};
    f32x4 a2 = {0.f, 0.f, 0.f, 0.f};
    f32x4 a3 = {0.f, 0.f, 0.f, 0.f};

    short8 fx[8];
    if (l == 0) {
      #pragma unroll
      for (int i = 0; i < 8; ++i) fx[i] = *(const short8*)(xw + i * 32);
    } else {
      wavewait(xflags, (unsigned)(t + 1));
      LD8SC(fx, xw);
      WAITV0;
    }
    #pragma unroll
    for (int i = 0; i < 8; ++i) {
      a0 = mfma16(WI[0 * 8 + i], fx[i], a0);
      a1 = mfma16(WI[1 * 8 + i], fx[i], a1);
      a2 = mfma16(WI[2 * 8 + i], fx[i], a2);
      a3 = mfma16(WI[3 * 8 + i], fx[i], a3);
    }

    short8 fh[8];
    if (t == 0) {
      const u16* hw = h0b + boff + kboff;
      #pragma unroll
      for (int i = 0; i < 8; ++i) fh[i] = *(const short8*)(hw + i * 32);
    } else {
      const u16* hw = Yout + (size_t)(t - 1) * (NB * H) + boff + kboff;
      wavewait(myflags, (unsigned)t);
      LD8SC(fh, hw);
      WAITV0;
    }
    #pragma unroll
    for (int i = 0; i < 8; ++i) {
      short8 w0 = *(const short8*)(smwv + 0 * 16384 + i * 512);
      short8 w1 = *(const short8*)(smwv + 1 * 16384 + i * 512);
      short8 w2 = *(const short8*)(smwv + 2 * 16384 + i * 512);
      short8 w3 = *(const short8*)(smwv + 3 * 16384 + i * 512);
      a0 = mfma16(w0, fh[i], a0);
      a1 = mfma16(w1, fh[i], a1);
      a2 = mfma16(w2, fh[i], a2);
      a3 = mfma16(w3, fh[i], a3);
    }

    // ---- cross-wave reduce: wave w keeps row-tile w, ships the rest via LDS ----
    if (wid != 0) lred[(0 * 4 + wid) * 64 + lane] = a0;
    if (wid != 1) lred[(1 * 4 + wid) * 64 + lane] = a1;
    if (wid != 2) lred[(2 * 4 + wid) * 64 + lane] = a2;
    if (wid != 3) lred[(3 * 4 + wid) * 64 + lane] = a3;
    __syncthreads();

    f32x4 z4 = bias4;
    if (wid == 0)      z4 += a0;
    else if (wid == 1) z4 += a1;
    else if (wid == 2) z4 += a2;
    else               z4 += a3;
    #pragma unroll
    for (int w2 = 0; w2 < 4; ++w2)
      if (w2 != wid) z4 += lred[(wid * 4 + w2) * 64 + lane];

    const float ig = sigm(z4[0]);
    const float fg = sigm(z4[1]);
    const float gg = tanhfast(z4[2]);
    const float og = sigm(z4[3]);
    c = fg * c + ig * gg;
    const float h = og * tanhfast(c);

    smh[b * 16 + wid * 4 + lg] = f2bf(h);
    if (t == SEQ - 1) {
      hfin[b * H + j] = h;
      cfin[b * H + j] = c;
    }

    __syncthreads();  // smh complete
    if (wid == 0) {
      if (lane < 32) {
        const int br = lane >> 1, half = lane & 1;
        u16x8 pv = *(const u16x8*)&smh[br * 16 + half * 8];
        const u16* dst = Yout + (size_t)t * (NB * H) + (size_t)br * H + jbase + half * 8;
        asm volatile("global_store_dwordx4 %0, %1, off sc0 sc1"
                     :: "v"(dst), "v"(pv) : "memory");
      }
      asm volatile("s_waitcnt vmcnt(0)" ::: "memory");  // h at coherence point
      if (lane == 0) {
        const unsigned tv = (unsigned)(t + 1);
        asm volatile("global_store_dword %0, %1, off sc0 sc1"
                     :: "v"(myflag_wr), "v"(tv) : "memory");
      }
    }
  }
}

// ---------------- bf16 GEMM C = A @ Bw^T + bias (round-0 proven) ----------------

__global__ __launch_bounds__(256, 1) void gemm_bt_bias(
    const u16* __restrict__ A, const u16* __restrict__ Bw,
    const float* __restrict__ bias, float* __restrict__ C, int N)
{
  __shared__ u16 As[128 * 64];
  __shared__ u16 Bs[128 * 64];
  const int tid = threadIdx.x;
  const int lane = tid & 63;
  const int wid = tid >> 6;
  const int m0 = blockIdx.x * 128;
  const int n0 = blockIdx.y * 128;
  const int wr = wid >> 1, wc = wid & 1;
  const int lr = lane >> 3;
  const int lc = (lane & 7) * 8;
  f32x4 acc[4][4] = {};

  for (int k0 = 0; k0 < H; k0 += 64) {
    __syncthreads();
    #pragma unroll
    for (int cc = 0; cc < 4; ++cc) {
      const int row = wid * 32 + cc * 8 + lr;
      __builtin_amdgcn_global_load_lds(
          (const __attribute__((address_space(1))) void*)(A + (size_t)(m0 + row) * H + k0 + lc),
          (__attribute__((address_space(3))) void*)(As + row * 64 + lc), 16, 0, 0);
      __builtin_amdgcn_global_load_lds(
          (const __attribute__((address_space(1))) void*)(Bw + (size_t)(n0 + row) * H + k0 + lc),
          (__attribute__((address_space(3))) void*)(Bs + row * 64 + lc), 16, 0, 0);
    }
    __syncthreads();
    #pragma unroll
    for (int ks = 0; ks < 2; ++ks) {
      short8 af[4], bfr[4];
      #pragma unroll
      for (int i = 0; i < 4; ++i) {
        af[i]  = *(const short8*)&As[(wr * 64 + i * 16 + (lane & 15)) * 64 + ks * 32 + (lane >> 4) * 8];
        bfr[i] = *(const short8*)&Bs[(wc * 64 + i * 16 + (lane & 15)) * 64 + ks * 32 + (lane >> 4) * 8];
      }
      #pragma unroll
      for (int i = 0; i < 4; ++i) {
        #pragma unroll
        for (int jj = 0; jj < 4; ++jj)
          acc[i][jj] = mfma16(af[i], bfr[jj], acc[i][jj]);
      }
    }
  }

  #pragma unroll
  for (int jj = 0; jj < 4; ++jj) {
    const int col = n0 + wc * 64 + jj * 16 + (lane & 15);
    const float bv = bias[col];
    #pragma unroll
    for (int i = 0; i < 4; ++i) {
      const int rbase = m0 + wr * 64 + i * 16 + (lane >> 4) * 4;
      #pragma unroll
      for (int r = 0; r < 4; ++r)
        C[(size_t)(rbase + r) * N + col] = acc[i][jj][r] + bv;
    }
  }
}

// ---------------- launch ----------------

extern "C" void kernel_launch(void* const* d_in, const int* in_sizes, int n_in,
                              void* d_out, int out_size, void* d_ws, size_t ws_size,
                              hipStream_t stream) {
  const int*   x    = (const int*)d_in[0];
  const float* h0   = (const float*)d_in[1];
  const float* c0   = (const float*)d_in[2];
  const float* emb  = (const float*)d_in[3];
  const float* W_ih = (const float*)d_in[4];
  const float* W_hh = (const float*)d_in[5];
  const float* b_ih = (const float*)d_in[6];
  const float* b_hh = (const float*)d_in[7];
  const float* fc_W = (const float*)d_in[8];
  const float* fc_b = (const float*)d_in[9];
  float* out = (float*)d_out;
  char* ws = (char*)d_ws;

  size_t off = 0;
  u16* WihB = (u16*)(ws + off); off += (size_t)NL * G4 * H * 2;   // 33.6 MB
  u16* WhhB = (u16*)(ws + off); off += (size_t)NL * G4 * H * 2;   // 33.6 MB
  u16* fcWB = (u16*)(ws + off); off += (size_t)VOCAB * H * 2;     // 65.5 MB
  u16* h0B  = (u16*)(ws + off); off += (size_t)NL * NB * H * 2;
  float* biasB = (float*)(ws + off); off += (size_t)NL * G4 * 4;
  u16* ybufs = (u16*)(ws + off); off += (size_t)(NL + 1) * YSZ * 2;  // 41.9 MB
  unsigned* bars = (unsigned*)(ws + off); off += 16384;
  if (ws_size < off) return;  // fail loudly rather than corrupt

  int n8;
  n8 = NL * G4 * H / 8;  cvt_bf16<<<(n8 + 255) / 256, 256, 0, stream>>>(W_ih, WihB, n8);
  n8 = NL * G4 * H / 8;  cvt_bf16<<<(n8 + 255) / 256, 256, 0, stream>>>(W_hh, WhhB, n8);
  n8 = VOCAB * H / 8;    cvt_bf16<<<(n8 + 255) / 256, 256, 0, stream>>>(fc_W, fcWB, n8);
  n8 = NL * NB * H / 8;  cvt_bf16<<<(n8 + 255) / 256, 256, 0, stream>>>(h0, h0B, n8);
  bias_sum<<<(NL * G4 + 255) / 256, 256, 0, stream>>>(b_ih, b_hh, biasB, NL * G4);
  zero_u32<<<16, 256, 0, stream>>>(bars, 4096);
  gather_emb<<<SEQ * NB, 256, 0, stream>>>(x, emb, ybufs);

  float* hfin = out + (size_t)SEQ * NB * VOCAB;
  float* cfin = hfin + (size_t)NL * NB * H;

  lstm_scan<<<NL * 64, 256, 147968, stream>>>(
      ybufs, ybufs, WihB, WhhB, biasB, h0B, c0, hfin, cfin, bars);

  gemm_bt_bias<<<dim3(32, 250), 256, 0, stream>>>(
      ybufs + (size_t)NL * YSZ, fcWB, fc_b, out, VOCAB);
}